// Round 1
// 1702.292 us; speedup vs baseline: 1.2944x; 1.2944x over previous
//
#include <hip/hip_runtime.h>
#include <float.h>

#define NQ     2048
#define DIM    512
#define MSZ    131072
#define TOPK   32
#define CH     512
#define NCHUNK (MSZ / CH)       // 256
#define TOPC   16               // candidates per (query, chunk)
#define CPQ    (NCHUNK * TOPC)  // 4096 packed candidates per query (unchanged)
#define QT     32               // queries per K1 block
#define MERGE  128              // exact-rescore set per query

typedef short  short8 __attribute__((ext_vector_type(8)));
typedef float  f32x4  __attribute__((ext_vector_type(4)));

__device__ __forceinline__ unsigned short f32_to_bf16_rne(float f) {
    union { float f; unsigned u; } v; v.f = f;
    unsigned r = v.u + 0x7FFFu + ((v.u >> 16) & 1u);
    return (unsigned short)(r >> 16);
}
// monotone (order-preserving) u16 transform of bf16 bits
__device__ __forceinline__ unsigned bf16_ordered(unsigned short k) {
    return (k & 0x8000u) ? (unsigned)(unsigned short)~k
                         : (unsigned)(k | 0x8000u);
}
// count of set bits in m among lanes strictly below mine
__device__ __forceinline__ int mbcnt64(unsigned long long m) {
    return (int)__builtin_amdgcn_mbcnt_hi(
        (unsigned)(m >> 32), __builtin_amdgcn_mbcnt_lo((unsigned)m, 0u));
}

// ---------------------------------------------------------------------------
// K0: f32 -> bf16 (RNE) conversion, float4 -> ushort4
// ---------------------------------------------------------------------------
__global__ __launch_bounds__(256) void k0_convert(
    const float* __restrict__ src, unsigned short* __restrict__ dst, int n4)
{
    int i = blockIdx.x * blockDim.x + threadIdx.x;
    const int stride = gridDim.x * blockDim.x;
    const float4* s4 = reinterpret_cast<const float4*>(src);
    ushort4* d4 = reinterpret_cast<ushort4*>(dst);
    for (; i < n4; i += stride) {
        const float4 v = s4[i];
        ushort4 o;
        o.x = f32_to_bf16_rne(v.x); o.y = f32_to_bf16_rne(v.y);
        o.z = f32_to_bf16_rne(v.z); o.w = f32_to_bf16_rne(v.w);
        d4[i] = o;
    }
}

// ---------------------------------------------------------------------------
// K1: bf16 MFMA scoring (32 queries x 512-row chunk) + per-(q,chunk) top-16
// via wave-per-query 16-bit threshold search using ballot+popcount (no
// cross-lane shuffle chains). Emits packed u32 candidates:
//   key16<<16 | (511 - local_row)   (desc u32 == key desc, row asc)
// Superset safety: need every exact global-top-32 member inside its chunk's
// top-16 by bf16 key. 32 balls into 256 chunks, P(some chunk >= 17) ~ 1e-30.
// CH=512 -> sc = 32 KB -> 5 blocks/CU (20 waves/CU) vs previous 2.
// XCD-chunked swizzle: each XCD owns 32 contiguous chunks so a chunk's B-tile
// (512 KB) stays resident in that XCD's 4 MB L2 across its 64 query blocks.
// ---------------------------------------------------------------------------
__global__ __launch_bounds__(256, 5) void k1_score_select(
    const unsigned short* __restrict__ qbf, const unsigned short* __restrict__ kbf,
    unsigned* __restrict__ cand)
{
    // dispatch slot -> (qt, chunk) with XCD ownership of chunk ranges
    const int s     = blockIdx.x;            // 0..16383
    const int xcd   = s & 7;                 // round-robin XCD assignment
    const int idx   = s >> 3;                // 0..2047 within XCD
    const int qt    = idx & 63;              // fast dim: chunk stays L2-hot
    const int chunk = xcd * (NCHUNK / 8) + (idx >> 6);   // 32 chunks per XCD

    const int tid  = threadIdx.x;
    const int w    = tid >> 6;      // wave 0..3 -> rows w*128..+127
    const int lane = tid & 63;
    const int l15  = lane & 15;
    const int kgrp = lane >> 4;     // k-subgroup 0..3

    __shared__ unsigned short sc[QT][CH];   // 32 KB bf16 scores

    // A: Q[qt*32 + mt*16 + l15][k]  row-major, 8 contiguous bf16 per lane
    const unsigned short* Abase = qbf + ((size_t)(qt * QT) + l15) * DIM + kgrp * 8;
    // B: K[chunk*512 + w*128 + st*64 + nt*16 + l15][k] (B^T pattern)
    const unsigned short* Bbase =
        kbf + ((size_t)chunk * CH + w * 128 + l15) * DIM + kgrp * 8;

    for (int st = 0; st < 2; ++st) {
        f32x4 acc[2][4];
        #pragma unroll
        for (int mt = 0; mt < 2; ++mt)
            #pragma unroll
            for (int nt = 0; nt < 4; ++nt)
                acc[mt][nt] = (f32x4){0.f, 0.f, 0.f, 0.f};

        #pragma unroll 4
        for (int ks = 0; ks < 16; ++ks) {
            short8 a[2], b[4];
            #pragma unroll
            for (int mt = 0; mt < 2; ++mt)
                a[mt] = *reinterpret_cast<const short8*>(
                    Abase + (size_t)mt * 16 * DIM + ks * 32);
            #pragma unroll
            for (int nt = 0; nt < 4; ++nt)
                b[nt] = *reinterpret_cast<const short8*>(
                    Bbase + ((size_t)st * 64 + nt * 16) * DIM + ks * 32);
            #pragma unroll
            for (int mt = 0; mt < 2; ++mt)
                #pragma unroll
                for (int nt = 0; nt < 4; ++nt)
                    acc[mt][nt] = __builtin_amdgcn_mfma_f32_16x16x32_bf16(
                        a[mt], b[nt], acc[mt][nt], 0, 0, 0);
        }
        // C/D layout: q = mt*16 + kgrp*4 + r, row = w*128 + st*64 + nt*16 + l15
        #pragma unroll
        for (int mt = 0; mt < 2; ++mt)
            #pragma unroll
            for (int nt = 0; nt < 4; ++nt)
                #pragma unroll
                for (int r = 0; r < 4; ++r) {
                    const int qloc = mt * 16 + kgrp * 4 + r;
                    const int rloc = w * 128 + st * 64 + nt * 16 + l15;
                    sc[qloc][rloc] = f32_to_bf16_rne(acc[mt][nt][r]);
                }
    }
    __syncthreads();

    // selection: wave w handles queries w, w+4, ..., w+28
    for (int qi = 0; qi < 8; ++qi) {
        const int qloc = w + qi * 4;
        // lane-strided u32 reads: 64 lanes x 4B consecutive -> conflict-free.
        // u32 at index lane + j*64 holds keys for rloc = 2*lane + 128*j (+1)
        const unsigned* row32 = reinterpret_cast<const unsigned*>(sc[qloc]);
        unsigned key[8];
        #pragma unroll
        for (int j = 0; j < 4; ++j) {
            const unsigned p = row32[lane + j * 64];
            key[2 * j]     = bf16_ordered((unsigned short)(p & 0xFFFFu));
            key[2 * j + 1] = bf16_ordered((unsigned short)(p >> 16));
        }
        // T = 16th largest of the 512 keys. Wave-wide counts via
        // ballot+popcount: no shuffle chains, count lands in SGPRs.
        unsigned T = 0;
        for (int b = 15; b >= 0; --b) {
            const unsigned trial = T | (1u << b);
            int cnt = 0;
            #pragma unroll
            for (int j = 0; j < 8; ++j)
                cnt += __popcll(__ballot(key[j] >= trial));
            if (cnt >= TOPC) T = trial;
        }
        int gtTot = 0;
        #pragma unroll
        for (int j = 0; j < 8; ++j)
            gtTot += __popcll(__ballot(key[j] > T));
        const int quotaEq = TOPC - gtTot;

        const int qid = qt * QT + qloc;
        unsigned* base = cand + ((size_t)qid * NCHUNK + chunk) * TOPC;
        int rgt = 0, req = 0;
        #pragma unroll
        for (int j = 0; j < 8; ++j) {
            const unsigned long long mgt = __ballot(key[j] > T);
            const unsigned long long meq = __ballot(key[j] == T);
            const unsigned rl = 2u * (unsigned)lane + 128u * (unsigned)(j >> 1)
                                + (unsigned)(j & 1);
            if (key[j] > T) {
                base[rgt + mbcnt64(mgt)] = (key[j] << 16) | (CH - 1u - rl);
            } else if (key[j] == T) {
                const int se = req + mbcnt64(meq);
                if (se < quotaEq) base[gtTot + se] = (T << 16) | (CH - 1u - rl);
            }
            rgt += __popcll(mgt);
            req += __popcll(meq);
        }
    }
}

// ---------------------------------------------------------------------------
// K2: wave per query. Radix-select top-128 of the 4096 packed candidates
// (ballot+popcount counting), rescore them with the BIT-EXACT np chain
// (ascending single-acc fmaf), emit top-32 by (exact score desc, row asc).
// ---------------------------------------------------------------------------
__global__ __launch_bounds__(256) void k2_merge_rescore(
    const float* __restrict__ q, const float* __restrict__ kmem,
    const unsigned* __restrict__ cand, int* __restrict__ final_idx)
{
    const int w    = threadIdx.x >> 6;
    const int lane = threadIdx.x & 63;
    const int qid  = blockIdx.x * 4 + w;

    __shared__ int   rows_s[4][MERGE];
    __shared__ float scs_s[4][MERGE];

    // load 64 candidates per lane, coalesced uint4
    unsigned v[64];
    const uint4* cp4 = reinterpret_cast<const uint4*>(cand + (size_t)qid * CPQ);
    #pragma unroll
    for (int j = 0; j < 16; ++j) {
        const uint4 t = cp4[j * 64 + lane];
        v[j * 4 + 0] = t.x; v[j * 4 + 1] = t.y;
        v[j * 4 + 2] = t.z; v[j * 4 + 3] = t.w;
    }
    // P = 128th largest u32 (ballot+popcount counting)
    unsigned P = 0;
    for (int b = 31; b >= 0; --b) {
        const unsigned trial = P | (1u << b);
        int cnt = 0;
        #pragma unroll
        for (int j = 0; j < 64; ++j) cnt += __popcll(__ballot(v[j] >= trial));
        if (cnt >= MERGE) P = trial;
    }
    int gt = 0, eq = 0;
    #pragma unroll
    for (int j = 0; j < 64; ++j) { gt += (v[j] > P); eq += (v[j] == P); }
    int pgt = gt, peq = eq;
    #pragma unroll
    for (int m = 1; m < 64; m <<= 1) {
        const int ag = __shfl_up(pgt, m);
        const int ae = __shfl_up(peq, m);
        if (lane >= m) { pgt += ag; peq += ae; }
    }
    const int totGT = __shfl(pgt, 63);
    pgt -= gt; peq -= eq;
    const int quotaEq = MERGE - totGT;
    {
        int sgt = pgt, seq = peq;
        #pragma unroll
        for (int j = 0; j < 64; ++j) {
            const int off  = (j & ~3) * 64 + lane * 4 + (j & 3); // u32 offset in query's cand block
            const int chnk = off >> 4;                            // 16 cands per chunk
            const int row  = chnk * CH + (CH - 1) - (int)(v[j] & (CH - 1u));
            if (v[j] > P) {
                rows_s[w][sgt++] = row;
            } else if (v[j] == P) {
                if (seq < quotaEq) rows_s[w][totGT + seq] = row;
                seq++;
            }
        }
    }
    __syncthreads();

    // bit-exact rescore: 2 interleaved ascending fmaf chains per lane
    {
#pragma clang fp contract(off)
        const float4* qr = reinterpret_cast<const float4*>(q + (size_t)qid * DIM);
        const int ra = rows_s[w][lane];
        const int rb = rows_s[w][lane + 64];
        const float4* ka = reinterpret_cast<const float4*>(kmem + (size_t)ra * DIM);
        const float4* kb = reinterpret_cast<const float4*>(kmem + (size_t)rb * DIM);
        float sa = 0.f, sb = 0.f;
        for (int d4 = 0; d4 < DIM / 4; ++d4) {
            const float4 qv = qr[d4];
            const float4 av = ka[d4];
            const float4 bv = kb[d4];
            sa = __builtin_fmaf(qv.x, av.x, sa); sb = __builtin_fmaf(qv.x, bv.x, sb);
            sa = __builtin_fmaf(qv.y, av.y, sa); sb = __builtin_fmaf(qv.y, bv.y, sb);
            sa = __builtin_fmaf(qv.z, av.z, sa); sb = __builtin_fmaf(qv.z, bv.z, sb);
            sa = __builtin_fmaf(qv.w, av.w, sa); sb = __builtin_fmaf(qv.w, bv.w, sb);
        }
        scs_s[w][lane]      = sa;
        scs_s[w][lane + 64] = sb;
    }
    __syncthreads();

    // exact top-32 of 128 by (score desc, row asc)
    float m0 = scs_s[w][lane],      m1 = scs_s[w][lane + 64];
    const int rr0 = rows_s[w][lane], rr1 = rows_s[w][lane + 64];
    for (int sel = 0; sel < TOPK; ++sel) {
        float bs; int bi;
        if (m0 > m1 || (m0 == m1 && rr0 < rr1)) { bs = m0; bi = rr0; }
        else                                    { bs = m1; bi = rr1; }
        #pragma unroll
        for (int m = 1; m < 64; m <<= 1) {
            const float os = __shfl_xor(bs, m);
            const int   oi = __shfl_xor(bi, m);
            if (os > bs || (os == bs && oi < bi)) { bs = os; bi = oi; }
        }
        if (lane == 0) final_idx[qid * TOPK + sel] = bi;
        if (rr0 == bi) m0 = -FLT_MAX;   // rows unique -> removes exactly winner
        if (rr1 == bi) m1 = -FLT_MAX;
    }
}

// ---------------------------------------------------------------------------
// K3: gather K and V rows into the output (k block then v block, flat f32)
// ---------------------------------------------------------------------------
__global__ __launch_bounds__(128) void k3_gather(
    const float* __restrict__ kmem, const float* __restrict__ vmem,
    const int* __restrict__ final_idx, float* __restrict__ out)
{
    const int b = blockIdx.x;
    const int t = threadIdx.x;
    const int idx = final_idx[b];
    const float4* kr = reinterpret_cast<const float4*>(kmem + (size_t)idx * DIM);
    const float4* vr = reinterpret_cast<const float4*>(vmem + (size_t)idx * DIM);
    float4* ok = reinterpret_cast<float4*>(out + (size_t)b * DIM);
    float4* ov = reinterpret_cast<float4*>(out + (size_t)NQ * TOPK * DIM + (size_t)b * DIM);
    ok[t] = kr[t];
    ov[t] = vr[t];
}

extern "C" void kernel_launch(void* const* d_in, const int* in_sizes, int n_in,
                              void* d_out, int out_size, void* d_ws, size_t ws_size,
                              hipStream_t stream)
{
    const float* q    = (const float*)d_in[0];
    const float* kmem = (const float*)d_in[1];
    const float* vmem = (const float*)d_in[2];
    float* out = (float*)d_out;

    // d_out scratch layout (consumed before K3 overwrites everything):
    // [0, 134217728)            bf16 K
    // [134217728, 136314880)    bf16 q
    // [136314880, 169869312)    packed candidates (u32)
    unsigned char* base = (unsigned char*)d_out;
    unsigned short* kbf = (unsigned short*)base;
    unsigned short* qbf = (unsigned short*)(base + (size_t)MSZ * DIM * 2);
    unsigned* cand = (unsigned*)(base + (size_t)MSZ * DIM * 2 + (size_t)NQ * DIM * 2);
    int* final_idx = (int*)d_ws;   // 256 KB, survives the gather

    k0_convert<<<4096, 256, 0, stream>>>(kmem, kbf, MSZ * DIM / 4);
    k0_convert<<<256, 256, 0, stream>>>(q, qbf, NQ * DIM / 4);
    k1_score_select<<<NQ / QT * NCHUNK, 256, 0, stream>>>(qbf, kbf, cand);  // 16384 blocks
    k2_merge_rescore<<<NQ / 4, 256, 0, stream>>>(q, kmem, cand, final_idx);
    k3_gather<<<NQ * TOPK, 128, 0, stream>>>(kmem, vmem, final_idx, out);
}